// Round 4
// baseline (373.475 us; speedup 1.0000x reference)
//
#include <hip/hip_runtime.h>

#define BB   2
#define TT   512
#define NF   6
#define DD   32
#define HIDD 128
#define NHH  4
#define HDD  32
#define GHH  32
#define FDD  128
#define LL   (TT*NF)      // 3072
#define EPSF 1e-5f
#define QT   16           // q-rows per half-tile
#define KT   32           // keys per LDS tile
#define NQT  (LL/QT)      // 192

// ---------------------------------------------------------------------------
// Kernel 1: gater + gated QKV, 4 tokens per 64-thread block (1536 blocks).
// Weight elements are loaded once per block and FMA'd against 4 tokens.
// Q/K/V written HEAD-MAJOR: [b, h, L, 32] for contiguous attn tile loads.
// ---------------------------------------------------------------------------
__global__ __launch_bounds__(64) void gate_qkv_kernel(
    const float* __restrict__ x,
    const float* __restrict__ g_ln_w, const float* __restrict__ g_ln_b,
    const float* __restrict__ g_w1,   const float* __restrict__ g_b1,
    const float* __restrict__ g_w2,   const float* __restrict__ g_b2,
    const float* __restrict__ q_w,    const float* __restrict__ q_b,
    const float* __restrict__ k_w,    const float* __restrict__ k_b,
    const float* __restrict__ v_w,    const float* __restrict__ v_b,
    float* __restrict__ Q, float* __restrict__ K, float* __restrict__ V)
{
    const int tok0 = blockIdx.x * 4;       // aligned: LL % 4 == 0
    const int lane = threadIdx.x;

    __shared__ float xs[4][DD];
    __shared__ float lns[4][DD];
    __shared__ float hs[4][GHH];
    __shared__ float gate_s[4];

    #pragma unroll
    for (int i = 0; i < 2; i++) {
        int idx = lane + i * 64;           // 0..127 = 4 tokens x 32 dims
        xs[idx >> 5][idx & 31] = x[(size_t)tok0 * DD + idx];
    }
    __syncthreads();

    const int tk = lane >> 5;              // half-wave: 0/1
    const int d5 = lane & 31;

    // LayerNorm (two tokens at a time across the two 32-lane halves)
    #pragma unroll
    for (int tt = 0; tt < 2; tt++) {
        int t = tt * 2 + tk;
        float xv = xs[t][d5];
        float s1 = xv, s2 = xv * xv;
        #pragma unroll
        for (int m = 16; m >= 1; m >>= 1) {
            s1 += __shfl_xor(s1, m, 32);
            s2 += __shfl_xor(s2, m, 32);
        }
        float mu  = s1 * (1.0f / DD);
        float var = s2 * (1.0f / DD) - mu * mu;
        float r   = rsqrtf(var + EPSF);
        lns[t][d5] = (xv - mu) * r * g_ln_w[d5] + g_ln_b[d5];
    }
    __syncthreads();

    // MLP hidden + SiLU
    #pragma unroll
    for (int tt = 0; tt < 2; tt++) {
        int t = tt * 2 + tk;
        float acc = g_b1[d5];
        #pragma unroll
        for (int d = 0; d < DD; d++) acc += lns[t][d] * g_w1[d * GHH + d5];
        hs[t][d5] = acc / (1.0f + __expf(-acc));
    }
    __syncthreads();

    // gate scalar per token
    #pragma unroll
    for (int tt = 0; tt < 2; tt++) {
        int t = tt * 2 + tk;
        float p = hs[t][d5] * g_w2[d5];
        #pragma unroll
        for (int m = 16; m >= 1; m >>= 1) p += __shfl_xor(p, m, 32);
        if (d5 == 0) gate_s[t] = 1.0f / (1.0f + __expf(-(p + g_b2[0])));
    }
    __syncthreads();

    // gated QKV: each thread owns cols {lane, lane+64} of each of Q/K/V
    float aq0[4], aq1[4], ak0[4], ak1[4], av0[4], av1[4];
    #pragma unroll
    for (int t = 0; t < 4; t++) {
        aq0[t] = q_b[lane]; aq1[t] = q_b[lane + 64];
        ak0[t] = k_b[lane]; ak1[t] = k_b[lane + 64];
        av0[t] = v_b[lane]; av1[t] = v_b[lane + 64];
    }
    #pragma unroll
    for (int d = 0; d < DD; d++) {
        float wq0 = q_w[d * HIDD + lane], wq1 = q_w[d * HIDD + lane + 64];
        float wk0 = k_w[d * HIDD + lane], wk1 = k_w[d * HIDD + lane + 64];
        float wv0 = v_w[d * HIDD + lane], wv1 = v_w[d * HIDD + lane + 64];
        #pragma unroll
        for (int t = 0; t < 4; t++) {
            float xd = xs[t][d];
            aq0[t] += xd * wq0; aq1[t] += xd * wq1;
            ak0[t] += xd * wk0; ak1[t] += xd * wk1;
            av0[t] += xd * wv0; av1[t] += xd * wv1;
        }
    }

    const int b  = tok0 / LL;
    const int l0 = tok0 - b * LL;
    const int hA = lane >> 5;              // head of col `lane` (0/1)
    #pragma unroll
    for (int t = 0; t < 4; t++) {
        float g = gate_s[t];
        size_t p0 = ((size_t)(b * NHH + hA)     * LL + l0 + t) * HDD + d5;
        size_t p1 = ((size_t)(b * NHH + 2 + hA) * LL + l0 + t) * HDD + d5;
        Q[p0] = aq0[t] * g;  Q[p1] = aq1[t] * g;
        K[p0] = ak0[t] * g;  K[p1] = ak1[t] * g;
        V[p0] = av0[t] * g;  V[p1] = av1[t] * g;
    }
}

// ---------------------------------------------------------------------------
// Kernel 2: flash attention, complementary-paired q-tiles for balance.
// Block = (pair pr, head, batch), 128 threads = 16 rows x 8 grp.
// Each thread owns row r of q-tile pr (A) AND row r of q-tile 191-pr (B):
// K/V LDS reads amortized over both rows. Work per block ~ constant.
// Causal prefix: row i attends exactly j < 6*(i/6+1).
// ---------------------------------------------------------------------------
__global__ __launch_bounds__(128) void attn_kernel(
    const float* __restrict__ Q, const float* __restrict__ K,
    const float* __restrict__ V, float* __restrict__ O)
{
    const int pr  = blockIdx.x;            // 0..95
    const int h   = blockIdx.y;
    const int b   = blockIdx.z;
    const int qtA = pr;
    const int qtB = (NQT - 1) - pr;        // 191..96
    const int tid = threadIdx.x;
    const int r   = tid >> 3;              // 0..15
    const int grp = tid & 7;
    const int igA = qtA * QT + r;
    const int igB = qtB * QT + r;
    const size_t hb = (size_t)(b * NHH + h) * LL;  // row base in [b,h,L,32]

    // stride 36: per ds_read_b128 instr the 8 grp-rows hit disjoint bank
    // quads (4*(8jj+grp)+4c4 mod 32 covers all 32 banks), 8-way broadcast.
    __shared__ __align__(16) float Kt[KT][36];
    __shared__ __align__(16) float Vt[KT][36];

    const float scale = 0.17677669529663688f;  // 1/sqrt(32)
    float qA[32], qB[32], oA[32], oB[32];
    {
        const float4* qa = (const float4*)(Q + (hb + igA) * HDD);
        const float4* qb = (const float4*)(Q + (hb + igB) * HDD);
        #pragma unroll
        for (int i = 0; i < 8; i++) {
            float4 ta = qa[i], tb = qb[i];
            qA[4*i+0]=ta.x*scale; qA[4*i+1]=ta.y*scale; qA[4*i+2]=ta.z*scale; qA[4*i+3]=ta.w*scale;
            qB[4*i+0]=tb.x*scale; qB[4*i+1]=tb.y*scale; qB[4*i+2]=tb.z*scale; qB[4*i+3]=tb.w*scale;
        }
    }
    #pragma unroll
    for (int i = 0; i < 32; i++) { oA[i] = 0.0f; oB[i] = 0.0f; }

    float mA = -1e30f, lA = 0.0f, mB = -1e30f, lB = 0.0f;
    const int jmaxA    = (igA / NF + 1) * NF;
    const int jmaxB    = (igB / NF + 1) * NF;
    const int jmaxAblk = ((qtA * QT + QT - 1) / NF + 1) * NF;
    const int jmaxBblk = ((qtB * QT + QT - 1) / NF + 1) * NF;
    const int ntiles   = (jmaxBblk + KT - 1) / KT;

    for (int kt = 0; kt < ntiles; kt++) {
        const int j0 = kt * KT;
        __syncthreads();
        #pragma unroll
        for (int i = 0; i < 2; i++) {
            int idx = tid + i * 128;       // 0..255 float4 slots per array
            int jr  = idx >> 3;
            int c4  = idx & 7;
            size_t gb = (hb + j0 + jr) * HDD;
            ((float4*)&Kt[jr][0])[c4] = ((const float4*)(K + gb))[c4];
            ((float4*)&Vt[jr][0])[c4] = ((const float4*)(V + gb))[c4];
        }
        __syncthreads();

        // ---- B rows (long prefix, active nearly every tile) ----
        {
            const int jend = jmaxB - j0;
            float p[4];
            #pragma unroll
            for (int jj = 0; jj < 4; jj++) {
                const int j = jj * 8 + grp;
                const float* kr = &Kt[j][0];
                float acc = 0.0f;
                #pragma unroll
                for (int d = 0; d < 32; d++) acc += qB[d] * kr[d];
                p[jj] = (j < jend) ? acc : -1e30f;
            }
            float tmax = fmaxf(fmaxf(p[0], p[1]), fmaxf(p[2], p[3]));
            tmax = fmaxf(tmax, __shfl_xor(tmax, 1));
            tmax = fmaxf(tmax, __shfl_xor(tmax, 2));
            tmax = fmaxf(tmax, __shfl_xor(tmax, 4));
            const float mn   = fmaxf(mB, tmax);
            const float corr = __expf(mB - mn);
            mB = mn;
            float ls = 0.0f;
            #pragma unroll
            for (int jj = 0; jj < 4; jj++) { p[jj] = __expf(p[jj] - mn); ls += p[jj]; }
            lB = lB * corr + ls;
            #pragma unroll
            for (int d = 0; d < 32; d++) oB[d] *= corr;
            #pragma unroll
            for (int jj = 0; jj < 4; jj++) {
                const float* vr = &Vt[jj * 8 + grp][0];
                const float pe = p[jj];
                #pragma unroll
                for (int d = 0; d < 32; d++) oB[d] += pe * vr[d];
            }
        }

        // ---- A rows (short prefix) — block-uniform skip once done ----
        if (j0 < jmaxAblk) {
            const int jend = jmaxA - j0;
            float p[4];
            #pragma unroll
            for (int jj = 0; jj < 4; jj++) {
                const int j = jj * 8 + grp;
                const float* kr = &Kt[j][0];
                float acc = 0.0f;
                #pragma unroll
                for (int d = 0; d < 32; d++) acc += qA[d] * kr[d];
                p[jj] = (j < jend) ? acc : -1e30f;
            }
            float tmax = fmaxf(fmaxf(p[0], p[1]), fmaxf(p[2], p[3]));
            tmax = fmaxf(tmax, __shfl_xor(tmax, 1));
            tmax = fmaxf(tmax, __shfl_xor(tmax, 2));
            tmax = fmaxf(tmax, __shfl_xor(tmax, 4));
            const float mn   = fmaxf(mA, tmax);
            const float corr = __expf(mA - mn);
            mA = mn;
            float ls = 0.0f;
            #pragma unroll
            for (int jj = 0; jj < 4; jj++) { p[jj] = __expf(p[jj] - mn); ls += p[jj]; }
            lA = lA * corr + ls;
            #pragma unroll
            for (int d = 0; d < 32; d++) oA[d] *= corr;
            #pragma unroll
            for (int jj = 0; jj < 4; jj++) {
                const float* vr = &Vt[jj * 8 + grp][0];
                const float pe = p[jj];
                #pragma unroll
                for (int d = 0; d < 32; d++) oA[d] += pe * vr[d];
            }
        }
    }

    // combine the 8 grp-partials per row, write token-major [b, L, 128]
    lA += __shfl_xor(lA, 1); lA += __shfl_xor(lA, 2); lA += __shfl_xor(lA, 4);
    lB += __shfl_xor(lB, 1); lB += __shfl_xor(lB, 2); lB += __shfl_xor(lB, 4);
    #pragma unroll
    for (int d = 0; d < 32; d++) {
        float va = oA[d];
        va += __shfl_xor(va, 1); va += __shfl_xor(va, 2); va += __shfl_xor(va, 4);
        oA[d] = va;
        float vb = oB[d];
        vb += __shfl_xor(vb, 1); vb += __shfl_xor(vb, 2); vb += __shfl_xor(vb, 4);
        oB[d] = vb;
    }
    const float invA = 1.0f / lA, invB = 1.0f / lB;
    float4 wa, wb;
    wa.x = oA[grp*4+0]*invA; wa.y = oA[grp*4+1]*invA;
    wa.z = oA[grp*4+2]*invA; wa.w = oA[grp*4+3]*invA;
    wb.x = oB[grp*4+0]*invB; wb.y = oB[grp*4+1]*invB;
    wb.z = oB[grp*4+2]*invB; wb.w = oB[grp*4+3]*invB;
    *((float4*)(O + ((size_t)(b * LL + igA)) * HIDD + h * HDD) + grp) = wa;
    *((float4*)(O + ((size_t)(b * LL + igB)) * HIDD + h * HDD) + grp) = wb;
}

// ---------------------------------------------------------------------------
// Kernel 3: mean-pool -> o-proj -> LN -> f-proj -> SiLU. Block per (t, b).
// ---------------------------------------------------------------------------
__global__ __launch_bounds__(128) void final_kernel(
    const float* __restrict__ A,
    const float* __restrict__ o_w,    const float* __restrict__ o_b,
    const float* __restrict__ f_ln_w, const float* __restrict__ f_ln_b,
    const float* __restrict__ f_w,    const float* __restrict__ f_b,
    float* __restrict__ out)
{
    const int t = blockIdx.x;
    const int b = blockIdx.y;
    const int d = threadIdx.x;   // 0..127

    __shared__ float ms[HIDD];
    __shared__ float lnbuf[HIDD];
    __shared__ float w1[2], w2[2];

    float acc = 0.0f;
    #pragma unroll
    for (int f = 0; f < NF; f++)
        acc += A[((size_t)(b * LL + t * NF + f)) * HIDD + d];
    acc *= (1.0f / NF);
    ms[d] = acc;
    __syncthreads();

    float ov = o_b[d];
    for (int k = 0; k < HIDD; k++) ov += ms[k] * o_w[k * HIDD + d];

    float s1 = ov, s2 = ov * ov;
    #pragma unroll
    for (int m = 32; m >= 1; m >>= 1) { s1 += __shfl_xor(s1, m); s2 += __shfl_xor(s2, m); }
    if ((d & 63) == 0) { w1[d >> 6] = s1; w2[d >> 6] = s2; }
    __syncthreads();
    float S1 = w1[0] + w1[1], S2 = w2[0] + w2[1];
    float mu  = S1 * (1.0f / HIDD);
    float var = S2 * (1.0f / HIDD) - mu * mu;
    float r   = rsqrtf(var + EPSF);
    float lnv = (ov - mu) * r * f_ln_w[d] + f_ln_b[d];
    lnbuf[d] = lnv;
    __syncthreads();

    float fv = f_b[d];
    for (int k = 0; k < HIDD; k++) fv += lnbuf[k] * f_w[k * HIDD + d];
    fv = fv / (1.0f + __expf(-fv));

    out[((size_t)(b * TT + t)) * FDD + d] = fv;
}

// ---------------------------------------------------------------------------
extern "C" void kernel_launch(void* const* d_in, const int* in_sizes, int n_in,
                              void* d_out, int out_size, void* d_ws, size_t ws_size,
                              hipStream_t stream)
{
    const float* x      = (const float*)d_in[0];
    const float* g_ln_w = (const float*)d_in[1];
    const float* g_ln_b = (const float*)d_in[2];
    const float* g_w1   = (const float*)d_in[3];
    const float* g_b1   = (const float*)d_in[4];
    const float* g_w2   = (const float*)d_in[5];
    const float* g_b2   = (const float*)d_in[6];
    const float* q_w    = (const float*)d_in[7];
    const float* q_b    = (const float*)d_in[8];
    const float* k_w    = (const float*)d_in[9];
    const float* k_b    = (const float*)d_in[10];
    const float* v_w    = (const float*)d_in[11];
    const float* v_b    = (const float*)d_in[12];
    const float* o_w    = (const float*)d_in[13];
    const float* o_b    = (const float*)d_in[14];
    const float* f_ln_w = (const float*)d_in[15];
    const float* f_ln_b = (const float*)d_in[16];
    const float* f_w    = (const float*)d_in[17];
    const float* f_b    = (const float*)d_in[18];

    const size_t stride = (size_t)BB * NHH * LL * HDD;   // 786432 floats
    float* Qw = (float*)d_ws;
    float* Kw = Qw + stride;
    float* Vw = Kw + stride;
    float* Aw = Vw + stride;                             // [B, L, HID]

    gate_qkv_kernel<<<(BB * LL) / 4, 64, 0, stream>>>(
        x, g_ln_w, g_ln_b, g_w1, g_b1, g_w2, g_b2,
        q_w, q_b, k_w, k_b, v_w, v_b, Qw, Kw, Vw);

    attn_kernel<<<dim3(NQT / 2, NHH, BB), 128, 0, stream>>>(Qw, Kw, Vw, Aw);

    final_kernel<<<dim3(TT, BB), 128, 0, stream>>>(
        Aw, o_w, o_b, f_ln_w, f_ln_b, f_w, f_b, (float*)d_out);
}